// Round 16
// baseline (292.809 us; speedup 1.0000x reference)
//
#include <hip/hip_runtime.h>
#include <hip/hip_bf16.h>

#define NB 8192   // batch
#define ND 1024   // feature dim

typedef int   i32x4 __attribute__((ext_vector_type(4)));
typedef int   i32x8 __attribute__((ext_vector_type(8)));
typedef float f32x4 __attribute__((ext_vector_type(4)));

// async global -> LDS, 16B per lane. LDS dest = wave-uniform base + lane*16.
__device__ inline void gload_lds16(const void* g, void* l) {
    __builtin_amdgcn_global_load_lds(
        (const __attribute__((address_space(1))) unsigned int*)g,
        (__attribute__((address_space(3))) unsigned int*)l,
        16, 0, 0);
}

#define BARRIER() asm volatile("s_barrier" ::: "memory")
#define VMCNT0()  asm volatile("s_waitcnt vmcnt(0)" ::: "memory")
#define LGKM0()   asm volatile("s_waitcnt lgkmcnt(0)" ::: "memory")

// ---------------------------------------------------------------------------
// Kernel 1: per-row L2 norms (f32) + fp8-e4m3 conversion into FRAGMENT-PACKED
// layout. Panel p = row>>7 (131072 B), K-tile kt = c>>7 (16384 B). Within a
// tile: byte addr = frag*(2048) + half*1024 + lane*16 + (c&15), where
// frag = (row>>4)&7, lane = ((c>>5)&3)*16 + (row&15), half = (c>>4)&1.
// This makes gemm staging perfectly linear and fragment reads conflict-free.
// ---------------------------------------------------------------------------
__global__ __launch_bounds__(256) void prep_kernel(
    const float* __restrict__ A, const float* __restrict__ Bm,
    unsigned char* __restrict__ wa2, unsigned char* __restrict__ wb2,
    float* __restrict__ na, float* __restrict__ nb)
{
    int b = blockIdx.x;
    int wid = threadIdx.x >> 6, lane = threadIdx.x & 63;
    bool isA = (b < 2048);
    int row = (isA ? b : b - 2048) * 4 + wid;
    const float*   rp  = (isA ? A : Bm) + (size_t)row * ND;
    unsigned char* dst = (isA ? wa2 : wb2);

    const size_t pbase = (size_t)(row >> 7) * 131072 + ((row >> 4) & 7) * 2048;
    const int    r15   = row & 15;

    float ss = 0.f;
#pragma unroll
    for (int t = 0; t < 4; ++t) {
        int c = lane * 4 + t * 256;
        float4 v = *reinterpret_cast<const float4*>(rp + c);
        ss += v.x * v.x + v.y * v.y + v.z * v.z + v.w * v.w;
        int u = __builtin_amdgcn_cvt_pk_fp8_f32(v.x, v.y, 0, false);
        u     = __builtin_amdgcn_cvt_pk_fp8_f32(v.z, v.w, u, true);
        size_t addr = pbase + (size_t)(c >> 7) * 16384 + ((c >> 4) & 1) * 1024
                    + (((c >> 5) & 3) * 16 + r15) * 16 + (c & 15);
        *reinterpret_cast<unsigned int*>(dst + addr) = (unsigned int)u;
    }
#pragma unroll
    for (int off = 32; off; off >>= 1) ss += __shfl_xor(ss, off);
    if (lane == 0) (isA ? na : nb)[row] = sqrtf(ss);
}

// ---------------------------------------------------------------------------
// Kernel 2: label histogram (integer LDS atomics -> deterministic).
// ---------------------------------------------------------------------------
__global__ __launch_bounds__(256) void hist_kernel(
    const int* __restrict__ labels, int* __restrict__ hist)
{
    __shared__ int h[128];
    int tid = threadIdx.x;
    if (tid < 128) h[tid] = 0;
    __syncthreads();
    for (int i = tid; i < NB; i += 256) atomicAdd(&h[labels[i]], 1);
    __syncthreads();
    if (tid < 128) hist[tid] = h[tid];
}

// ---------------------------------------------------------------------------
// Kernel 3: 128x128-tile MX-fp8 GEMM (m148 recipe on the R8/R10 structure).
// BK=128 bytes -> 8 K-iters. 4 waves (2x2), mfma_scale 16x16x128, scales=1.0.
// LDS dbuf 2 x (A 16K | B 16K) = 64 KiB -> 2 blocks/CU. Fragment-packed
// workspace => staging = 8 perfectly-linear gload_lds / tile, fragment reads
// = base + lane*16 (conflict-free by construction, no swizzle anywhere).
// Per iter: STAGE(t+1) -> COMPUTE(t) (16 ds_read_b128 pairs + 16 MFMA/wave)
// -> sched_barrier -> vmcnt(0) (covered by compute; full drain = no tail
// miscount) -> lgkmcnt(0) (race fix, R10-proven) -> s_barrier.
// Epilogue: scale to cos, write C, fused per-row loss partials.
// ---------------------------------------------------------------------------
__global__ __launch_bounds__(256) void gemm_cos(
    const unsigned char* __restrict__ wa2, const unsigned char* __restrict__ wb2,
    const float* __restrict__ na, const float* __restrict__ nb,
    const int* __restrict__ labels,
    float* __restrict__ C, float* __restrict__ pe, float* __restrict__ pm)
{
    __shared__ __align__(16) unsigned char lds8[65536];

    const int bid = blockIdx.x;                 // 4096 blocks
    const int tm  = (bid & 7) * 8 + ((bid >> 3) & 7);   // XCD owns 8 tm rows
    const int tn  = bid >> 6;                            // B streams

    const int tid  = threadIdx.x;
    const int lane = tid & 63;
    const int wid  = tid >> 6;
    const int wr   = wid >> 1, wc = wid & 1;
    const int l15  = lane & 15, lg = lane >> 4;

    const int m0 = tm * 128, n0 = tn * 128;

    // Staging: global tile chunk is laid out exactly as LDS wants it.
    const unsigned char* pA = wa2 + (size_t)tm * 131072 + tid * 16;
    const unsigned char* pB = wb2 + (size_t)tn * 131072 + tid * 16;
    const int stW = wid * 1024;     // wave-uniform dest base per 4KB issue

    // Fragment reads: frag f at f*2048; halves at +0 / +1024; lane*16.
    const int afb = wr * 8192 + lane * 16;            // + m*2048 (A @ buf+0)
    const int bqb = 16384 + wc * 8192 + lane * 16;    // + n*2048 (B @ buf+16K)

    f32x4 acc[4][4];
#pragma unroll
    for (int i = 0; i < 4; ++i)
#pragma unroll
        for (int j = 0; j < 4; ++j) acc[i][j] = (f32x4){0.f, 0.f, 0.f, 0.f};

#define STAGE(kt, BUF) do { \
    _Pragma("unroll") \
    for (int i_ = 0; i_ < 4; ++i_) { \
        gload_lds16(pA + (kt) * 16384 + i_ * 4096, \
                    &lds8[(BUF) + i_ * 4096 + stW]); \
        gload_lds16(pB + (kt) * 16384 + i_ * 4096, \
                    &lds8[(BUF) + 16384 + i_ * 4096 + stW]); \
    } } while (0)

// one fragment operand: two adjacent conflict-free b128 reads -> v8i32
#define RD32(off) __builtin_shufflevector( \
    *reinterpret_cast<const i32x4*>(&lds8[(off)]), \
    *reinterpret_cast<const i32x4*>(&lds8[(off) + 1024]), 0, 1, 2, 3, 4, 5, 6, 7)

#define COMPUTE(BUF) do { \
    i32x8 bq[4]; \
    _Pragma("unroll") \
    for (int n_ = 0; n_ < 4; ++n_) bq[n_] = RD32((BUF) + bqb + n_ * 2048); \
    _Pragma("unroll") \
    for (int m_ = 0; m_ < 4; ++m_) { \
        i32x8 am = RD32((BUF) + afb + m_ * 2048); \
        _Pragma("unroll") \
        for (int n_ = 0; n_ < 4; ++n_) \
            acc[m_][n_] = __builtin_amdgcn_mfma_scale_f32_16x16x128_f8f6f4( \
                am, bq[n_], acc[m_][n_], 0, 0, 0, 127, 0, 127); \
    } } while (0)

    // Prologue: stage tile 0 into buf0.
    STAGE(0, 0);
    VMCNT0();
    BARRIER();

#pragma unroll
    for (int t = 0; t < 8; ++t) {
        const int cb = (t & 1) * 32768;
        if (t < 7) STAGE(t + 1, cb ^ 32768);    // issue-early
        COMPUTE(cb);                            // ~550+ cyc of cover
        __builtin_amdgcn_sched_barrier(0);
        VMCNT0();                               // stage(t+1) landed
        LGKM0();                                // reads drained: handoff safe
        BARRIER();
    }

#undef COMPUTE
#undef RD32
#undef STAGE

    // ---------------- epilogue: cos write + fused loss partials ------------
    __syncthreads();                 // LDS reusable
    float* pl = reinterpret_cast<float*>(lds8);  // [128 rows][2 wc][2] floats

    float nbv[4]; int labc[4];
#pragma unroll
    for (int n = 0; n < 4; ++n) {
        int c = n0 + wc * 64 + n * 16 + l15;
        nbv[n] = nb[c]; labc[n] = labels[c];
    }

#pragma unroll
    for (int m = 0; m < 4; ++m) {
#pragma unroll
        for (int jj = 0; jj < 4; ++jj) {
            int rl = wr * 64 + m * 16 + lg * 4 + jj;   // 0..127
            int r  = m0 + rl;
            float nav = na[r]; int labr = labels[r];
            float es = 0.f, ms = 0.f;
#pragma unroll
            for (int n = 0; n < 4; ++n) {
                int c = n0 + wc * 64 + n * 16 + l15;
                float v = acc[m][n][jj] / fmaxf(nav * nbv[n], 1e-8f);
                C[(size_t)r * NB + c] = v;
                es += __expf(v);
                ms += (labc[n] == labr) ? v : 0.f;
            }
#pragma unroll
            for (int off = 1; off < 16; off <<= 1) {
                es += __shfl_xor(es, off);
                ms += __shfl_xor(ms, off);
            }
            if (l15 == 0) {
                int o = rl * 4 + wc * 2;
                pl[o] = es; pl[o + 1] = ms;
            }
        }
    }
    __syncthreads();
    if (tid < 128) {
        float es = pl[tid * 4]     + pl[tid * 4 + 2];
        float ms = pl[tid * 4 + 1] + pl[tid * 4 + 3];
        pe[tn * NB + m0 + tid] = es;
        pm[tn * NB + m0 + tid] = ms;
    }
}

// ---------------------------------------------------------------------------
// Kernel 4: reduce 64 column-tile partials -> per-row loss.
// ---------------------------------------------------------------------------
__global__ __launch_bounds__(256) void loss_final(
    const float* __restrict__ pe, const float* __restrict__ pm,
    const int* __restrict__ labels, const int* __restrict__ hist,
    float* __restrict__ per_row)
{
    int row = blockIdx.x * 256 + threadIdx.x;
    float es = 0.f, ms = 0.f;
#pragma unroll
    for (int t = 0; t < 64; ++t) {
        es += pe[t * NB + row];
        ms += pm[t * NB + row];
    }
    per_row[row] = logf(es) - ms / (float)hist[labels[row]];
}

// ---------------------------------------------------------------------------
// Kernel 5: deterministic mean of per_row -> out[0]
// ---------------------------------------------------------------------------
__global__ __launch_bounds__(256) void finalize(
    const float* __restrict__ per_row, float* __restrict__ out)
{
    __shared__ float sm[256];
    float s = 0.f;
    for (int i = threadIdx.x; i < NB; i += 256) s += per_row[i];
    sm[threadIdx.x] = s;
    __syncthreads();
    for (int k = 128; k; k >>= 1) {
        if (threadIdx.x < k) sm[threadIdx.x] += sm[threadIdx.x + k];
        __syncthreads();
    }
    if (threadIdx.x == 0) out[0] = sm[0] * (1.0f / (float)NB);
}

extern "C" void kernel_launch(void* const* d_in, const int* in_sizes, int n_in,
                              void* d_out, int out_size, void* d_ws, size_t ws_size,
                              hipStream_t stream) {
    const int*   labels = (const int*)d_in[0];
    const float* A      = (const float*)d_in[1];
    const float* Bm     = (const float*)d_in[2];
    float* out = (float*)d_out;

    // workspace layout (~21 MB)
    char* ws = (char*)d_ws;
    unsigned char* wa2 = (unsigned char*)(ws);                  // 8 MB
    unsigned char* wb2 = (unsigned char*)(ws + 8388608);        // 8 MB
    float* na      = (float*)(ws + 16777216);                   // 32 KB
    float* nb      = (float*)(ws + 16809984);                   // 32 KB
    float* per_row = (float*)(ws + 16842752);                   // 32 KB
    int*   hist    = (int*)  (ws + 16875520);                   // 512 B
    float* pe      = (float*)(ws + 16908288);                   // 2 MB
    float* pm      = (float*)(ws + 19005440);                   // 2 MB

    float* cosm = out + 1;   // out[0]=loss, out[1..] = cos_score row-major

    prep_kernel<<<4096, 256, 0, stream>>>(A, Bm, wa2, wb2, na, nb);
    hist_kernel<<<1,    256, 0, stream>>>(labels, hist);
    gemm_cos   <<<4096, 256, 0, stream>>>(wa2, wb2, na, nb, labels, cosm, pe, pm);
    loss_final <<<32,   256, 0, stream>>>(pe, pm, labels, hist, per_row);
    finalize   <<<1,    256, 0, stream>>>(per_row, out);
}